// Round 3
// baseline (581.471 us; speedup 1.0000x reference)
//
#include <hip/hip_runtime.h>
#include <cstdint>
#include <cstddef>

// Problem constants (match reference setup_inputs)
#define Bb   256
#define Tt   250
#define DIN  700
#define Hh   128
#define DOUT 20

// ---------------------------------------------------------------------------
// Phase 1: H1[b*T+t][h] = x[b][t][:] @ W1[:,h] + b1[h]
// M=64000, K=700, N=128. 128x128 tile, BK=20, 256 threads, 8x8 micro-tile.
// Ast padded to BM+4 (132 floats = 528 B row stride): the transposed staging
// writes (5 lanes share `row`) land on banks {0,4,8,12,16}+row instead of
// all on bank row%32; 528 B keeps rows 16-B aligned for ds_read_b128.
// ---------------------------------------------------------------------------
constexpr int BM  = 128;
constexpr int BK  = 20;
constexpr int BN  = 128;
constexpr int BMP = BM + 4;   // padded row length for Ast

__global__ __launch_bounds__(256, 2) void gemm_h1(const float* __restrict__ x,
                                                  const float* __restrict__ W1,
                                                  const float* __restrict__ b1,
                                                  float* __restrict__ H1) {
    __shared__ float Ast[BK][BMP];  // x tile, TRANSPOSED: Ast[k][m], padded
    __shared__ float Bs[BK][BN];    // W1 tile, natural

    const int tid = threadIdx.x;
    const int tx  = tid & 15;       // col group: cols tx*8 .. +7
    const int ty  = tid >> 4;       // row group: rows ty*8 .. +7
    const int m0  = blockIdx.x * BM;

    float acc[8][8];
#pragma unroll
    for (int r = 0; r < 8; ++r)
#pragma unroll
        for (int c = 0; c < 8; ++c) acc[r][c] = 0.f;

    for (int k0 = 0; k0 < DIN; k0 += BK) {
        // Stage A: 128 rows x 20 k = 640 float4 (coalesced global read,
        // scattered-but-conflict-light LDS writes thanks to the +4 pad).
#pragma unroll
        for (int idx = tid; idx < 640; idx += 256) {
            int row = idx / 5;
            int kq  = (idx - row * 5) * 4;
            const float4 v =
                *(const float4*)&x[(size_t)(m0 + row) * DIN + (k0 + kq)];
            Ast[kq + 0][row] = v.x;
            Ast[kq + 1][row] = v.y;
            Ast[kq + 2][row] = v.z;
            Ast[kq + 3][row] = v.w;
        }
        // Stage B: 20 rows x 128 cols = 640 float4 (fully coalesced both ways)
#pragma unroll
        for (int idx = tid; idx < 640; idx += 256) {
            int kr = idx >> 5;
            int nq = (idx & 31) * 4;
            *(float4*)&Bs[kr][nq] =
                *(const float4*)&W1[(size_t)(k0 + kr) * BN + nq];
        }
        __syncthreads();

#pragma unroll
        for (int kk = 0; kk < BK; ++kk) {
            float a[8], bv[8];
            *(float4*)&a[0]  = *(const float4*)&Ast[kk][ty * 8];
            *(float4*)&a[4]  = *(const float4*)&Ast[kk][ty * 8 + 4];
            *(float4*)&bv[0] = *(const float4*)&Bs[kk][tx * 8];
            *(float4*)&bv[4] = *(const float4*)&Bs[kk][tx * 8 + 4];
#pragma unroll
            for (int r = 0; r < 8; ++r)
#pragma unroll
                for (int c = 0; c < 8; ++c)
                    acc[r][c] = fmaf(a[r], bv[c], acc[r][c]);
        }
        __syncthreads();
    }

    float bb[8];
#pragma unroll
    for (int c = 0; c < 8; ++c) bb[c] = b1[tx * 8 + c];

#pragma unroll
    for (int r = 0; r < 8; ++r) {
        size_t row = (size_t)(m0 + ty * 8 + r);
        float4 o0, o1;
        o0.x = acc[r][0] + bb[0]; o0.y = acc[r][1] + bb[1];
        o0.z = acc[r][2] + bb[2]; o0.w = acc[r][3] + bb[3];
        o1.x = acc[r][4] + bb[4]; o1.y = acc[r][5] + bb[5];
        o1.z = acc[r][6] + bb[6]; o1.w = acc[r][7] + bb[7];
        *(float4*)&H1[row * Hh + tx * 8]     = o0;
        *(float4*)&H1[row * Hh + tx * 8 + 4] = o1;
    }
}

// ---------------------------------------------------------------------------
// Phase 2: recurrence, wave-autonomous. 256 blocks x 64 threads (1 wave =
// 1 batch row). Lane owns units {lane, lane+64}. Spike masks are two 64-bit
// SGPR ballots -> no barriers, no LDS lists. Gathers walk the masks with
// scalar ffs extraction batched 8-deep: 8 independent LDS/global loads in
// flight per wait, flag-padded tail (w * 0.0 terms are exact no-ops).
// Ascending-k order preserved (mask0 bits 0..63 then mask1 bits 64..127).
// W2 + rcW2 pair-interleaved in LDS (128 KB); rcW1 gathered from global
// (L2-hot, and its latency is hidden behind layer-2 of the same step).
// Readout hoisted: out = cnt2 @ W3 + T*b3.
// ---------------------------------------------------------------------------

// Extract up to 8 ascending set-bit indices from the 128-bit mask (m0,m1);
// flag = 0 for exhausted slots. Wave-uniform -> scalar pipe.
__device__ __forceinline__ void extract8(unsigned long long& m0,
                                         unsigned long long& m1,
                                         int* ks, float* fs) {
#pragma unroll
    for (int j = 0; j < 8; ++j) {
        const bool has0 = (m0 != 0ull);
        const bool has1 = (m1 != 0ull);
        const bool any  = has0 | has1;
        unsigned long long mm = has0 ? m0 : m1;
        int k = (int)__ffsll((unsigned long long)mm) - 1;   // -1 if mm==0
        ks[j] = any ? ((has0 ? 0 : 64) + k) : 0;
        fs[j] = any ? 1.f : 0.f;
        unsigned long long cl = mm & (mm - 1ull);
        if (has0)      m0 = cl;
        else if (has1) m1 = cl;
    }
}

// Gather from LDS matrix in pair-interleaved layout:
// sW[k*128 + 2*l] = M[k][l], sW[k*128 + 2*l + 1] = M[k][l+64]
__device__ __forceinline__ float2 gather_lds(const float* __restrict__ sW,
                                             unsigned long long m0,
                                             unsigned long long m1, int lane) {
    float ax = 0.f, ay = 0.f, bx = 0.f, by = 0.f;
    const int n = __popcll(m0) + __popcll(m1);
    int ks[8]; float fs[8];
    for (int done = 0; done < n; done += 8) {
        extract8(m0, m1, ks, fs);
        float2 w[8];
#pragma unroll
        for (int j = 0; j < 8; ++j)
            w[j] = *(const float2*)(sW + ks[j] * 128 + 2 * lane);
#pragma unroll
        for (int j = 0; j < 8; j += 2) {
            ax = fmaf(w[j].x,     fs[j],     ax);
            ay = fmaf(w[j].y,     fs[j],     ay);
            bx = fmaf(w[j + 1].x, fs[j + 1], bx);
            by = fmaf(w[j + 1].y, fs[j + 1], by);
        }
    }
    return make_float2(ax + bx, ay + by);
}

// Same walk but row-major global matrix (two dword loads per k).
__device__ __forceinline__ float2 gather_glb(const float* __restrict__ W,
                                             unsigned long long m0,
                                             unsigned long long m1, int lane) {
    float ax = 0.f, ay = 0.f, bx = 0.f, by = 0.f;
    const int n = __popcll(m0) + __popcll(m1);
    int ks[8]; float fs[8];
    for (int done = 0; done < n; done += 8) {
        extract8(m0, m1, ks, fs);
        float2 w[8];
#pragma unroll
        for (int j = 0; j < 8; ++j) {
            const float* p = W + ks[j] * Hh + lane;
            w[j].x = p[0];
            w[j].y = p[64];
        }
#pragma unroll
        for (int j = 0; j < 8; j += 2) {
            ax = fmaf(w[j].x,     fs[j],     ax);
            ay = fmaf(w[j].y,     fs[j],     ay);
            bx = fmaf(w[j + 1].x, fs[j + 1], bx);
            by = fmaf(w[j + 1].y, fs[j + 1], by);
        }
    }
    return make_float2(ax + bx, ay + by);
}

__global__ __launch_bounds__(64, 1) void recurrent(
    const float* __restrict__ H1,   const float* __restrict__ rcW1,
    const float* __restrict__ rcb1, const float* __restrict__ W2,
    const float* __restrict__ b2,   const float* __restrict__ rcW2,
    const float* __restrict__ rcb2, const float* __restrict__ W3,
    const float* __restrict__ b3,   float* __restrict__ out) {

    __shared__ float sW2[Hh * Hh];    // 64 KB, pair-interleaved
    __shared__ float sRc2[Hh * Hh];   // 64 KB, pair-interleaved
    __shared__ float scnt[Hh];

    const int lane = threadIdx.x;     // 0..63
    const int b    = blockIdx.x;

    // ---- stage W2, rcW2 pair-interleaved ----
    for (int idx = lane; idx < Hh * 64; idx += 64) {
        int k = idx >> 6, l = idx & 63;
        float2 p2, pr;
        p2.x = W2 [k * Hh + l];  p2.y = W2 [k * Hh + l + 64];
        pr.x = rcW2[k * Hh + l]; pr.y = rcW2[k * Hh + l + 64];
        *(float2*)&sW2 [k * Hh + 2 * l] = p2;
        *(float2*)&sRc2[k * Hh + 2 * l] = pr;
    }
    __syncthreads();

    const float rcb1x = rcb1[lane], rcb1y = rcb1[lane + 64];
    const float bb2x  = b2[lane]      + rcb2[lane];
    const float bb2y  = b2[lane + 64] + rcb2[lane + 64];
    const float* __restrict__ h1p = H1 + (size_t)b * Tt * Hh;

    float v1x = 0.f, v1y = 0.f, v2x = 0.f, v2y = 0.f;
    float cntx = 0.f, cnty = 0.f;
    float2 u1g = make_float2(0.f, 0.f);   // rcW1 gather for current step
    float2 u2g = make_float2(0.f, 0.f);   // rcW2 gather for current step

    float h1x = h1p[lane], h1y = h1p[lane + 64];

    for (int t = 0; t < Tt; ++t) {
        // ---- layer 1 LIF ----
        const float u1xv = h1x + rcb1x + u1g.x;
        const float u1yv = h1y + rcb1y + u1g.y;
        v1x = v1x + (u1xv - v1x) * 0.5f;
        v1y = v1y + (u1yv - v1y) * 0.5f;
        const bool s1x = (v1x >= 1.0f);
        const bool s1y = (v1y >= 1.0f);
        if (s1x) v1x = 0.f;
        if (s1y) v1y = 0.f;
        const unsigned long long M1a = __ballot((int)s1x);
        const unsigned long long M1b = __ballot((int)s1y);

        // prefetch next h1 pair (guard OOB at t=249)
        const int tn = (t + 1 < Tt) ? (t + 1) : (Tt - 1);
        h1x = h1p[(size_t)tn * Hh + lane];
        h1y = h1p[(size_t)tn * Hh + lane + 64];

        // ---- layer 2: critical gather (W2 over fresh s1) ----
        const float2 hw2 = gather_lds(sW2, M1a, M1b, lane);
        const float u2xv = bb2x + hw2.x + u2g.x;
        const float u2yv = bb2y + hw2.y + u2g.y;
        v2x = v2x + (u2xv - v2x) * 0.5f;
        v2y = v2y + (u2yv - v2y) * 0.5f;
        const bool s2x = (v2x >= 1.0f);
        const bool s2y = (v2y >= 1.0f);
        if (s2x) v2x = 0.f;
        if (s2y) v2y = 0.f;
        cntx += s2x ? 1.f : 0.f;
        cnty += s2y ? 1.f : 0.f;
        const unsigned long long M2a = __ballot((int)s2x);
        const unsigned long long M2b = __ballot((int)s2y);

        // ---- off-path gathers for next step ----
        u1g = gather_glb(rcW1, M1a, M1b, lane);
        u2g = gather_lds(sRc2, M2a, M2b, lane);
    }

    // ---- readout: out[b] = cnt2 @ W3 + T*b3 ----
    scnt[lane]      = cntx;
    scnt[lane + 64] = cnty;
    __syncthreads();
    if (lane < DOUT) {
        float o = (float)Tt * b3[lane];
#pragma unroll 8
        for (int k = 0; k < Hh; ++k) o += scnt[k] * W3[k * DOUT + lane];
        out[b * DOUT + lane] = o;
    }
}

// ---------------------------------------------------------------------------
extern "C" void kernel_launch(void* const* d_in, const int* in_sizes, int n_in,
                              void* d_out, int out_size, void* d_ws, size_t ws_size,
                              hipStream_t stream) {
    const float* x    = (const float*)d_in[0];
    const float* W1   = (const float*)d_in[1];
    const float* b1   = (const float*)d_in[2];
    const float* rcW1 = (const float*)d_in[3];
    const float* rcb1 = (const float*)d_in[4];
    const float* W2   = (const float*)d_in[5];
    const float* b2   = (const float*)d_in[6];
    const float* rcW2 = (const float*)d_in[7];
    const float* rcb2 = (const float*)d_in[8];
    const float* W3   = (const float*)d_in[9];
    const float* b3   = (const float*)d_in[10];

    float* out = (float*)d_out;
    float* H1  = (float*)d_ws;   // 64000 x 128 f32 = 32.77 MB

    gemm_h1<<<(Bb * Tt) / BM, 256, 0, stream>>>(x, W1, b1, H1);
    recurrent<<<Bb, 64, 0, stream>>>(H1, rcW1, rcb1, W2, b2, rcW2, rcb2, W3,
                                     b3, out);
}